// Round 1
// baseline (649.518 us; speedup 1.0000x reference)
//
#include <hip/hip_runtime.h>
#include <hip/hip_bf16.h>

#define NB    2048
#define LSEQ  200
#define EMB   32
#define TDIM  128
#define COND  160
#define ROWS  321   // 2*COND + 1
#define MASK_T 48

__device__ __forceinline__ float bf2f(unsigned short u) {
    union { unsigned int i; float f; } v; v.i = ((unsigned int)u) << 16; return v.f;
}
__device__ __forceinline__ unsigned short f2bf(float f) {
    union { float f; unsigned int i; } v; v.f = f;
    unsigned int x = v.i;
    return (unsigned short)((x + 0x7fffu + ((x >> 16) & 1u)) >> 16);  // RNE
}

__global__ __launch_bounds__(256, 2)
void fused_diffusion_cond(const int*   __restrict__ tp,
                          const int*   __restrict__ loc,
                          const float* __restrict__ emb,
                          const int*   __restrict__ st,        // [B][L][2]
                          const float* __restrict__ loc_emb,   // [V][32]
                          const float* __restrict__ noise,
                          const int*   __restrict__ tstep,
                          const float* __restrict__ w1,        // [160][160]
                          const float* __restrict__ w2,        // [160][160]
                          const float* __restrict__ b2,
                          const float* __restrict__ wc,
                          const float* __restrict__ alpha_hat,
                          float* __restrict__ out)             // [B][321][32]
{
    __shared__ unsigned short ue[LSEQ][COND];   // 64,000 B, bf16
    __shared__ float score[LSEQ];               // 800 B
    __shared__ float f160[COND];                // 640 B: side -> mean -> m1 -> uemb

    const int b   = blockIdx.x;
    const int tid = threadIdx.x;
    float* outb = out + (size_t)b * (ROWS * EMB);

    // ---- Phase 0: side = [te(tp) | le(loc)] into f160; noisy row 320 ----
    if (tid < TDIM) {
        const int   half = tid >> 1;
        const float dv   = __expf(-0.14391156f * (float)half);  // 10000^(-half/64)
        const float ang  = (float)tp[b] * dv;
        f160[tid] = (tid & 1) ? __cosf(ang) : __sinf(ang);
    } else if (tid < COND) {
        f160[tid] = loc_emb[(size_t)(loc[b] - 1) * EMB + (tid - TDIM)];
    } else if (tid < COND + EMB) {
        const int   e = tid - COND;
        const float a = alpha_hat[tstep[b]];
        outb[320 * EMB + e] = sqrtf(a) * emb[b * EMB + e]
                            + sqrtf(1.0f - a) * noise[b * EMB + e];
    }
    __syncthreads();

    // ---- Phase 1: write ST_info rows (broadcast side) + build ue in LDS ----
    for (int idx = tid; idx < COND * EMB; idx += 256)
        outb[idx] = f160[idx >> 5];

    for (int idx = tid; idx < LSEQ * COND; idx += 256) {
        const int l = idx / COND;
        const int k = idx - l * COND;
        const int2 sv = ((const int2*)st)[b * LSEQ + l];   // .x = s, .y = tt
        float v;
        if (k < EMB) {                                     // ue = [le2 | te2] (loc FIRST)
            v = loc_emb[(size_t)(sv.x - 1) * EMB + k];
        } else {
            const int   jj   = k - EMB;
            const int   half = jj >> 1;
            const float dv   = __expf(-0.14391156f * (float)half);
            const float ang  = (float)sv.y * dv;
            v = (jj & 1) ? __cosf(ang) : __sinf(ang);
            if (sv.y == MASK_T) v = 0.0f;
        }
        ue[l][k] = f2bf(v);
    }
    __syncthreads();

    // ---- Phase 2: mean over L -> f160 ----
    if (tid < COND) {
        float s = 0.0f;
        #pragma unroll 8
        for (int l = 0; l < LSEQ; ++l) s += bf2f(ue[l][tid]);
        f160[tid] = s * (1.0f / 200.0f);
    }
    __syncthreads();

    // ---- Phase 3: m1 = b2 + mean @ w1^T (per-c, into f160) ----
    float m1r = 0.0f;
    if (tid < COND) {
        m1r = b2[tid];
        const float* w1r = w1 + tid * COND;
        #pragma unroll 8
        for (int k = 0; k < COND; ++k) m1r = fmaf(f160[k], w1r[k], m1r);
    }
    __syncthreads();
    if (tid < COND) f160[tid] = m1r;
    __syncthreads();

    // ---- Phase 4: logits = ue @ w2^T; attn=sigmoid(logit+m1); score = attn@wc ----
    // thread (ty=tid>>4, tx=tid&15): 13 l's (l = i*16+ty), 5 c's per j (c = j*80+tx*5+cc)
    const int tx = tid & 15;
    const int ty = tid >> 4;
    float scpart[13];
    #pragma unroll
    for (int i = 0; i < 13; ++i) scpart[i] = 0.0f;

    #pragma unroll 1
    for (int j = 0; j < 2; ++j) {
        const int c0 = j * 80 + tx * 5;
        float acc[5][13];
        #pragma unroll
        for (int cc = 0; cc < 5; ++cc)
            #pragma unroll
            for (int i = 0; i < 13; ++i) acc[cc][i] = 0.0f;

        for (int k = 0; k < COND; k += 4) {
            float4 wv[5];
            #pragma unroll
            for (int cc = 0; cc < 5; ++cc)
                wv[cc] = *(const float4*)(w2 + (c0 + cc) * COND + k);
            #pragma unroll
            for (int i = 0; i < 13; ++i) {
                const int l  = i * 16 + ty;
                const int lr = (l < LSEQ) ? l : (LSEQ - 1);   // clamp; results discarded
                const ushort4 u = *(const ushort4*)&ue[lr][k];
                const float u0 = bf2f(u.x), u1 = bf2f(u.y), u2 = bf2f(u.z), u3 = bf2f(u.w);
                #pragma unroll
                for (int cc = 0; cc < 5; ++cc) {
                    acc[cc][i] = fmaf(u0, wv[cc].x, acc[cc][i]);
                    acc[cc][i] = fmaf(u1, wv[cc].y, acc[cc][i]);
                    acc[cc][i] = fmaf(u2, wv[cc].z, acc[cc][i]);
                    acc[cc][i] = fmaf(u3, wv[cc].w, acc[cc][i]);
                }
            }
        }
        #pragma unroll
        for (int cc = 0; cc < 5; ++cc) {
            const float m1v = f160[c0 + cc];
            const float wcv = wc[c0 + cc];
            #pragma unroll
            for (int i = 0; i < 13; ++i) {
                const float att = 1.0f / (1.0f + __expf(-(acc[cc][i] + m1v)));
                scpart[i] = fmaf(att, wcv, scpart[i]);
            }
        }
    }
    // reduce score over the 16 tx lanes (lane bits 0..3), one writer per l
    #pragma unroll
    for (int i = 0; i < 13; ++i) {
        float v = scpart[i];
        v += __shfl_xor(v, 1);
        v += __shfl_xor(v, 2);
        v += __shfl_xor(v, 4);
        v += __shfl_xor(v, 8);
        const int l = i * 16 + ty;
        if (tx == 0 && l < LSEQ) score[l] = v;
    }
    __syncthreads();

    // ---- Phase 5: uemb[c] = sum_l score[l]*ue[l][c]; write user_info rows ----
    if (tid < COND) {
        float uer = 0.0f;
        #pragma unroll 8
        for (int l = 0; l < LSEQ; ++l) uer = fmaf(score[l], bf2f(ue[l][tid]), uer);
        f160[tid] = uer;          // m1 no longer needed (all reads pre-barrier)
    }
    __syncthreads();
    for (int idx = tid; idx < COND * EMB; idx += 256)
        outb[COND * EMB + idx] = f160[idx >> 5];
}

extern "C" void kernel_launch(void* const* d_in, const int* in_sizes, int n_in,
                              void* d_out, int out_size, void* d_ws, size_t ws_size,
                              hipStream_t stream) {
    const int*   tp        = (const int*)  d_in[0];
    const int*   loc       = (const int*)  d_in[1];
    const float* emb       = (const float*)d_in[2];
    const int*   st        = (const int*)  d_in[3];
    const float* loc_emb   = (const float*)d_in[4];
    const float* noise     = (const float*)d_in[5];
    const int*   tstep     = (const int*)  d_in[6];
    const float* w1        = (const float*)d_in[7];
    const float* w2        = (const float*)d_in[8];
    const float* b2        = (const float*)d_in[9];
    const float* wc        = (const float*)d_in[10];
    const float* alpha_hat = (const float*)d_in[11];
    float* out = (float*)d_out;

    const int nb = in_sizes[0];   // 2048
    fused_diffusion_cond<<<nb, 256, 0, stream>>>(tp, loc, emb, st, loc_emb, noise,
                                                 tstep, w1, w2, b2, wc, alpha_hat, out);
}

// Round 2
// 176.664 us; speedup vs baseline: 3.6766x; 3.6766x over previous
//
#include <hip/hip_runtime.h>
#include <hip/hip_bf16.h>

#define LSEQ   200
#define LPAD   208
#define EMB    32
#define TDIM   128
#define COND   160
#define ROWS   321
#define MASK_T 48
#define UE_LDB 336      // ue row stride in bytes (168 bf16; 21 16B-chunks -> conflict-free MFMA A reads)

typedef __attribute__((ext_vector_type(8))) short  short8;
typedef __attribute__((ext_vector_type(4))) float  f32x4;

__device__ __forceinline__ float bf2f(unsigned short u) {
    union { unsigned int i; float f; } v; v.i = ((unsigned int)u) << 16; return v.f;
}
__device__ __forceinline__ unsigned int f2bf(float f) {
    union { float f; unsigned int i; } v; v.f = f;
    unsigned int x = v.i;
    return ((x + 0x7fffu + ((x >> 16) & 1u)) >> 16);   // RNE, low 16 bits
}
__device__ __forceinline__ unsigned int pack2(float lo, float hi) {
    return f2bf(lo) | (f2bf(hi) << 16);
}

// ---- pre-kernel: w2 fp32[160][160] -> bf16 row-major in d_ws ----
__global__ void cvt_w2_bf16(const float* __restrict__ w2, unsigned short* __restrict__ w2b) {
    const int i = blockIdx.x * 256 + threadIdx.x;          // 6400 float4 total
    const float4 v = ((const float4*)w2)[i];
    ((uint2*)w2b)[i] = make_uint2(pack2(v.x, v.y), pack2(v.z, v.w));
}

__global__ __launch_bounds__(256, 2)
void fused_cond(const int*   __restrict__ tp,
                const int*   __restrict__ loc,
                const float* __restrict__ emb,
                const int*   __restrict__ st,        // [B][L][2]
                const float* __restrict__ loc_emb,   // [V][32]
                const float* __restrict__ noise,
                const int*   __restrict__ tstep,
                const float* __restrict__ w1,        // [160][160] fp32
                const unsigned short* __restrict__ w2b,  // [160][160] bf16
                const float* __restrict__ b2,
                const float* __restrict__ wc,
                const float* __restrict__ alpha_hat,
                float* __restrict__ out)             // [B][321][32]
{
    __shared__ unsigned char ueb[LPAD * UE_LDB];   // 69,888 B  (bf16, padded stride)
    __shared__ float score[LPAD];                  // 832 B
    __shared__ float f160[COND];                   // side -> mean -> uemb
    __shared__ float m1s[COND];                    // m1 (attn bias row)
    __shared__ float wcs[COND];
    __shared__ float dtab[64];                     // 10000^(-h/64)

    const int b   = blockIdx.x;
    const int tid = threadIdx.x;
    float* outb = out + (size_t)b * (ROWS * EMB);

    // ---- Phase 0 ----
    if (tid < 64) dtab[tid] = __expf(-0.14391156f * (float)tid);
    if (tid < LPAD) score[tid] = 0.0f;
    if (tid < COND) wcs[tid] = wc[tid];
    if (tid < TDIM) {
        const float dv  = __expf(-0.14391156f * (float)(tid >> 1));
        const float ang = (float)tp[b] * dv;
        f160[tid] = (tid & 1) ? __cosf(ang) : __sinf(ang);
    } else if (tid < COND) {
        f160[tid] = loc_emb[(size_t)(loc[b] - 1) * EMB + (tid - TDIM)];
    } else if (tid < COND + EMB) {
        const int   e = tid - COND;
        const float a = alpha_hat[tstep[b]];
        outb[320 * EMB + e] = sqrtf(a) * emb[b * EMB + e]
                            + sqrtf(1.0f - a) * noise[b * EMB + e];
    }
    __syncthreads();

    // ---- Phase 1: ST_info broadcast rows + build ue (bf16, padded) ----
    float4* ob4 = (float4*)outb;
    #pragma unroll
    for (int t = 0; t < 5; ++t) {                      // 160*8 = 1280 float4
        const int i4 = tid + t * 256;
        const float v = f160[i4 >> 3];
        ob4[i4] = make_float4(v, v, v, v);
    }
    for (int ci = tid; ci < LPAD * 20; ci += 256) {    // 16B chunks: l in [0,208), ch in [0,20)
        const int l  = ci / 20;
        const int ch = ci - l * 20;
        uint4 val = make_uint4(0, 0, 0, 0);
        if (l < LSEQ) {
            const int2 sv = ((const int2*)st)[b * LSEQ + l];   // .x = s, .y = tt
            if (ch < 4) {                                      // le2: cols 0..31
                const float4* lrow = (const float4*)(loc_emb + (size_t)(sv.x - 1) * EMB);
                const float4 v0 = lrow[ch * 2], v1 = lrow[ch * 2 + 1];
                val = make_uint4(pack2(v0.x, v0.y), pack2(v0.z, v0.w),
                                 pack2(v1.x, v1.y), pack2(v1.z, v1.w));
            } else if (sv.y != MASK_T) {                       // te2: cols 32..159
                const int h0 = ch * 4 - 16;
                const float ttv = (float)sv.y;
                const float a0 = ttv * dtab[h0],     a1 = ttv * dtab[h0 + 1];
                const float a2 = ttv * dtab[h0 + 2], a3 = ttv * dtab[h0 + 3];
                val = make_uint4(pack2(__sinf(a0), __cosf(a0)),
                                 pack2(__sinf(a1), __cosf(a1)),
                                 pack2(__sinf(a2), __cosf(a2)),
                                 pack2(__sinf(a3), __cosf(a3)));
            }
        }
        *(uint4*)(ueb + l * UE_LDB + ch * 16) = val;
    }
    __syncthreads();

    // ---- Phase 2: mean over L ----
    if (tid < COND) {
        float s0 = 0.0f, s1 = 0.0f;
        for (int l = 0; l < LSEQ; l += 2) {
            s0 += bf2f(*(const unsigned short*)(ueb + l * UE_LDB + 2 * tid));
            s1 += bf2f(*(const unsigned short*)(ueb + (l + 1) * UE_LDB + 2 * tid));
        }
        f160[tid] = (s0 + s1) * (1.0f / 200.0f);
    }
    __syncthreads();

    // ---- Phase 3: m1 = b2 + mean @ w1^T ----
    if (tid < COND) {
        float m = b2[tid];
        const float4* w1r = (const float4*)(w1 + tid * COND);
        #pragma unroll 4
        for (int k4 = 0; k4 < COND / 4; ++k4) {
            const float4 wv = w1r[k4];
            m += f160[k4 * 4 + 0] * wv.x + f160[k4 * 4 + 1] * wv.y
               + f160[k4 * 4 + 2] * wv.z + f160[k4 * 4 + 3] * wv.w;
        }
        m1s[tid] = m;
    }
    __syncthreads();

    // ---- Phase 4: MFMA GEMM logits = ue @ w2^T, fused sigmoid/score epilogue ----
    // wave w owns n-tiles {w, w+4} (+ {w+8} for w<2); B-fragments resident in VGPRs.
    const int wv = tid >> 6, lane = tid & 63, lc = lane & 15, lg = lane >> 4;
    const int nn = (wv < 2) ? 3 : 2;

    short8 bfr0[5], bfr1[5], bfr2[5];
    {
        const unsigned short* r0 = w2b + ((wv)     * 16 + lc) * COND + lg * 8;
        const unsigned short* r1 = w2b + ((wv + 4) * 16 + lc) * COND + lg * 8;
        #pragma unroll
        for (int kt = 0; kt < 5; ++kt) {
            bfr0[kt] = *(const short8*)(r0 + kt * 32);
            bfr1[kt] = *(const short8*)(r1 + kt * 32);
        }
        if (nn == 3) {
            const unsigned short* r2 = w2b + ((wv + 8) * 16 + lc) * COND + lg * 8;
            #pragma unroll
            for (int kt = 0; kt < 5; ++kt) bfr2[kt] = *(const short8*)(r2 + kt * 32);
        }
    }
    const float m10 = m1s[wv * 16 + lc],      wv0 = wcs[wv * 16 + lc];
    const float m11 = m1s[(wv + 4) * 16 + lc], wv1 = wcs[(wv + 4) * 16 + lc];
    float m12 = 0.0f, wv2 = 0.0f;
    if (nn == 3) { m12 = m1s[(wv + 8) * 16 + lc]; wv2 = wcs[(wv + 8) * 16 + lc]; }

    for (int m = 0; m < 13; ++m) {
        f32x4 a0 = {0,0,0,0}, a1 = {0,0,0,0}, a2 = {0,0,0,0};
        const unsigned char* ab = ueb + (m * 16 + lc) * UE_LDB + lg * 16;
        #pragma unroll
        for (int kt = 0; kt < 5; ++kt) {
            const short8 av = *(const short8*)(ab + kt * 64);
            a0 = __builtin_amdgcn_mfma_f32_16x16x32_bf16(av, bfr0[kt], a0, 0, 0, 0);
            a1 = __builtin_amdgcn_mfma_f32_16x16x32_bf16(av, bfr1[kt], a1, 0, 0, 0);
            if (nn == 3)
                a2 = __builtin_amdgcn_mfma_f32_16x16x32_bf16(av, bfr2[kt], a2, 0, 0, 0);
        }
        // D layout: col = lc (our c within n-tile), row = m*16 + lg*4 + r
        f32x4 sc;
        #pragma unroll
        for (int r = 0; r < 4; ++r) {
            float s = wv0 / (1.0f + __expf(-(a0[r] + m10)))
                    + wv1 / (1.0f + __expf(-(a1[r] + m11)));
            if (nn == 3) s += wv2 / (1.0f + __expf(-(a2[r] + m12)));
            sc[r] = s;
        }
        #pragma unroll
        for (int sh = 1; sh < 16; sh <<= 1) {
            sc[0] += __shfl_xor(sc[0], sh);
            sc[1] += __shfl_xor(sc[1], sh);
            sc[2] += __shfl_xor(sc[2], sh);
            sc[3] += __shfl_xor(sc[3], sh);
        }
        if (lc == 0) {
            #pragma unroll
            for (int r = 0; r < 4; ++r)
                atomicAdd(&score[m * 16 + lg * 4 + r], sc[r]);
        }
    }
    __syncthreads();

    // ---- Phase 5: uemb = score^T @ ue; broadcast user_info rows ----
    if (tid < COND) {
        float u0 = 0.0f, u1 = 0.0f;
        for (int l = 0; l < LSEQ; l += 2) {
            u0 += score[l]     * bf2f(*(const unsigned short*)(ueb + l * UE_LDB + 2 * tid));
            u1 += score[l + 1] * bf2f(*(const unsigned short*)(ueb + (l + 1) * UE_LDB + 2 * tid));
        }
        f160[tid] = u0 + u1;
    }
    __syncthreads();
    #pragma unroll
    for (int t = 0; t < 5; ++t) {
        const int i4 = tid + t * 256;
        const float v = f160[i4 >> 3];
        ob4[COND * 8 + i4] = make_float4(v, v, v, v);
    }
}

extern "C" void kernel_launch(void* const* d_in, const int* in_sizes, int n_in,
                              void* d_out, int out_size, void* d_ws, size_t ws_size,
                              hipStream_t stream) {
    const int*   tp        = (const int*)  d_in[0];
    const int*   loc       = (const int*)  d_in[1];
    const float* emb       = (const float*)d_in[2];
    const int*   st        = (const int*)  d_in[3];
    const float* loc_emb   = (const float*)d_in[4];
    const float* noise     = (const float*)d_in[5];
    const int*   tstep     = (const int*)  d_in[6];
    const float* w1        = (const float*)d_in[7];
    const float* w2        = (const float*)d_in[8];
    const float* b2        = (const float*)d_in[9];
    const float* wc        = (const float*)d_in[10];
    const float* alpha_hat = (const float*)d_in[11];
    float* out = (float*)d_out;

    unsigned short* w2b = (unsigned short*)d_ws;       // 51,200 B scratch

    cvt_w2_bf16<<<25, 256, 0, stream>>>(w2, w2b);      // 6400 float4 / 256
    const int nb = in_sizes[0];                         // 2048
    fused_cond<<<nb, 256, 0, stream>>>(tp, loc, emb, st, loc_emb, noise,
                                       tstep, w1, w2b, b2, wc, alpha_hat, out);
}

// Round 3
// 153.489 us; speedup vs baseline: 4.2317x; 1.1510x over previous
//
#include <hip/hip_runtime.h>
#include <hip/hip_bf16.h>

#define LSEQ   200
#define LPAD   208
#define EMB    32
#define TDIM   128
#define COND   160
#define ROWS   321
#define MASK_T 48
#define UE_LDB 336      // ue row stride bytes (168 bf16 = 21 16B chunks; MFMA A reads 2-way max)

typedef __attribute__((ext_vector_type(8))) short  short8;
typedef __attribute__((ext_vector_type(4))) float  f32x4;

__device__ __forceinline__ float bf2f(unsigned short u) {
    union { unsigned int i; float f; } v; v.i = ((unsigned int)u) << 16; return v.f;
}
__device__ __forceinline__ unsigned int f2bf(float f) {
    union { float f; unsigned int i; } v; v.f = f;
    unsigned int x = v.i;
    return ((x + 0x7fffu + ((x >> 16) & 1u)) >> 16);   // RNE, low 16
}
__device__ __forceinline__ unsigned int pack2(float lo, float hi) {
    return f2bf(lo) | (f2bf(hi) << 16);
}

// ---- prep: w2 fp32->bf16 (blocks 0..24) + te_tab[49][128] bf16 (blocks 25..37) ----
__global__ void prep(const float* __restrict__ w2, unsigned short* __restrict__ w2b,
                     unsigned short* __restrict__ te_tab) {
    const int bid = blockIdx.x;
    if (bid < 25) {
        const int i = bid * 256 + threadIdx.x;             // 6400 float4
        const float4 v = ((const float4*)w2)[i];
        ((uint2*)w2b)[i] = make_uint2(pack2(v.x, v.y), pack2(v.z, v.w));
    } else {
        const int i = (bid - 25) * 256 + threadIdx.x;      // 49*64 = 3136 sin/cos pairs
        if (i < 49 * 64) {
            const int pos = i >> 6, h = i & 63;
            const float a = (float)pos * __expf(-0.14391156f * (float)h);
            ((unsigned int*)te_tab)[i] = pack2(__sinf(a), __cosf(a));
        }
    }
}

__global__ __launch_bounds__(512, 4)
void fused_cond(const int*   __restrict__ tp,
                const int*   __restrict__ loc,
                const float* __restrict__ emb,
                const int*   __restrict__ st,        // [B][L][2]
                const float* __restrict__ loc_emb,   // [V][32] fp32
                const float* __restrict__ noise,
                const int*   __restrict__ tstep,
                const float* __restrict__ w1,        // [160][160] fp32
                const unsigned short* __restrict__ w2b,    // [160][160] bf16
                const unsigned short* __restrict__ te_tab, // [49][128] bf16
                const float* __restrict__ b2,
                const float* __restrict__ wc,
                const float* __restrict__ alpha_hat,
                float* __restrict__ out)             // [B][321][32]
{
    __shared__ __attribute__((aligned(16))) unsigned char ueb[LPAD * UE_LDB]; // 69,888 B
    __shared__ float score[LPAD];
    __shared__ float f160[COND];    // side
    __shared__ float m1s[COND];
    __shared__ float wcs[COND];
    __shared__ float macc[COND];    // mean*200 accumulator
    __shared__ float uacc[COND];    // uemb accumulator

    const int b   = blockIdx.x;
    const int tid = threadIdx.x;
    float* outb = out + (size_t)b * (ROWS * EMB);
    float4* ob4 = (float4*)outb;

    // ---- P0: init + side + noisy row ----
    if (tid < LPAD) score[tid] = 0.0f;
    if (tid >= 256 && tid < 256 + COND) { macc[tid - 256] = 0.0f; uacc[tid - 256] = 0.0f; }
    if (tid >= 448 && tid < 448 + 49) { /* touch table into L1 (optional) */ }
    if (tid < TDIM) {
        f160[tid] = bf2f(te_tab[tp[b] * TDIM + tid]);
        if (tid < 32) wcs[tid + 128] = wc[tid + 128];
    } else if (tid < COND) {
        f160[tid] = loc_emb[(size_t)(loc[b] - 1) * EMB + (tid - TDIM)];
        wcs[tid - 128] = wc[tid - 128];
    } else if (tid < COND + EMB) {
        const int   e = tid - COND;
        const float a = alpha_hat[tstep[b]];
        outb[320 * EMB + e] = sqrtf(a) * emb[b * EMB + e]
                            + sqrtf(1.0f - a) * noise[b * EMB + e];
    } else if (tid < COND + EMB + 96) {
        wcs[tid - COND - EMB + 32] = wc[tid - COND - EMB + 32];
    }
    __syncthreads();

    // ---- P1: ST_info broadcast rows + build ue (table gather) ----
    for (int i4 = tid; i4 < COND * 8; i4 += 512) {
        const float v = f160[i4 >> 3];
        ob4[i4] = make_float4(v, v, v, v);
    }
    for (int ci = tid; ci < LPAD * 20; ci += 512) {      // 16B chunks
        const int l  = ci / 20;
        const int ch = ci - l * 20;
        uint4 val = make_uint4(0, 0, 0, 0);
        if (l < LSEQ) {
            const int2 sv = ((const int2*)st)[b * LSEQ + l];   // .x=s, .y=tt
            if (ch < 4) {                                      // le2: cols 0..31 (fp32->bf16)
                const float4* lrow = (const float4*)(loc_emb + (size_t)(sv.x - 1) * EMB);
                const float4 v0 = lrow[ch * 2], v1 = lrow[ch * 2 + 1];
                val = make_uint4(pack2(v0.x, v0.y), pack2(v0.z, v0.w),
                                 pack2(v1.x, v1.y), pack2(v1.z, v1.w));
            } else if (sv.y != MASK_T) {                       // te2: table row copy
                val = *(const uint4*)(te_tab + sv.y * TDIM + (ch - 4) * 8);
            }
        }
        *(uint4*)(ueb + l * UE_LDB + ch * 16) = val;
    }
    __syncthreads();

    // ---- b-fragment loads (global, overlap P2/P3) ----
    const int wv = tid >> 6, lane = tid & 63, lc = lane & 15, lg = lane >> 4;
    const int t0 = wv;
    const int nn = (wv < 2) ? 2 : 1;                     // waves 0,1 also own tiles 8,9
    short8 bfr0[5], bfr1[5];
    {
        const unsigned short* r0 = w2b + (t0 * 16 + lc) * COND + lg * 8;
        #pragma unroll
        for (int kt = 0; kt < 5; ++kt) bfr0[kt] = *(const short8*)(r0 + kt * 32);
        if (nn == 2) {
            const unsigned short* r1 = w2b + ((8 + wv) * 16 + lc) * COND + lg * 8;
            #pragma unroll
            for (int kt = 0; kt < 5; ++kt) bfr1[kt] = *(const short8*)(r1 + kt * 32);
        }
    }

    // ---- P2: column sums of ue (2-way row split) ----
    if (tid < 320) {
        const int part = tid >> 7 >> 1;                  // tid/256? no: compute below
    }
    if (tid < 320) {
        const int part = (tid < 160) ? 0 : 1;
        const int col  = tid - part * 160;
        const unsigned char* p = ueb + (part * 100) * UE_LDB + 2 * col;
        float s0 = 0.0f, s1 = 0.0f;
        #pragma unroll 4
        for (int l = 0; l < 100; l += 2) {
            s0 += bf2f(*(const unsigned short*)(p + l * UE_LDB));
            s1 += bf2f(*(const unsigned short*)(p + (l + 1) * UE_LDB));
        }
        atomicAdd(&macc[col], s0 + s1);
    }
    __syncthreads();

    // ---- P3: m1 = b2 + mean @ w1^T ----
    if (tid < COND) {
        float m = 0.0f;
        const float4* w1r = (const float4*)(w1 + tid * COND);
        #pragma unroll 4
        for (int k4 = 0; k4 < COND / 4; ++k4) {
            const float4 wv4 = w1r[k4];
            m += macc[k4 * 4 + 0] * wv4.x + macc[k4 * 4 + 1] * wv4.y
               + macc[k4 * 4 + 2] * wv4.z + macc[k4 * 4 + 3] * wv4.w;
        }
        m1s[tid] = b2[tid] + m * (1.0f / 200.0f);
    }
    __syncthreads();

    // ---- P4: MFMA logits + fused sigmoid/score ----
    const float m10 = m1s[t0 * 16 + lc],  wv0 = wcs[t0 * 16 + lc];
    float m11 = 0.0f, wv1 = 0.0f;
    if (nn == 2) { m11 = m1s[(8 + wv) * 16 + lc]; wv1 = wcs[(8 + wv) * 16 + lc]; }

    for (int m = 0; m < 13; ++m) {
        f32x4 a0 = {0,0,0,0}, a1 = {0,0,0,0};
        const unsigned char* ab = ueb + (m * 16 + lc) * UE_LDB + lg * 16;
        #pragma unroll
        for (int kt = 0; kt < 5; ++kt) {
            const short8 av = *(const short8*)(ab + kt * 64);
            a0 = __builtin_amdgcn_mfma_f32_16x16x32_bf16(av, bfr0[kt], a0, 0, 0, 0);
            if (nn == 2)
                a1 = __builtin_amdgcn_mfma_f32_16x16x32_bf16(av, bfr1[kt], a1, 0, 0, 0);
        }
        f32x4 sc;
        #pragma unroll
        for (int r = 0; r < 4; ++r) {
            float s = wv0 / (1.0f + __expf(-(a0[r] + m10)));
            if (nn == 2) s += wv1 / (1.0f + __expf(-(a1[r] + m11)));
            sc[r] = s;
        }
        #pragma unroll
        for (int sh = 1; sh < 16; sh <<= 1) {
            sc[0] += __shfl_xor(sc[0], sh);
            sc[1] += __shfl_xor(sc[1], sh);
            sc[2] += __shfl_xor(sc[2], sh);
            sc[3] += __shfl_xor(sc[3], sh);
        }
        if (lc == 0) {
            #pragma unroll
            for (int r = 0; r < 4; ++r)
                atomicAdd(&score[m * 16 + lg * 4 + r], sc[r]);
        }
    }
    __syncthreads();

    // ---- P5: uemb = score^T @ ue (2-way row split) ----
    if (tid < 320) {
        const int part = (tid < 160) ? 0 : 1;
        const int col  = tid - part * 160;
        const int l0   = part * 100;
        const unsigned char* p = ueb + l0 * UE_LDB + 2 * col;
        float u0 = 0.0f, u1 = 0.0f;
        #pragma unroll 4
        for (int l = 0; l < 100; l += 2) {
            u0 += score[l0 + l]     * bf2f(*(const unsigned short*)(p + l * UE_LDB));
            u1 += score[l0 + l + 1] * bf2f(*(const unsigned short*)(p + (l + 1) * UE_LDB));
        }
        atomicAdd(&uacc[col], u0 + u1);
    }
    __syncthreads();

    // ---- P6: user_info broadcast rows ----
    for (int i4 = tid; i4 < COND * 8; i4 += 512) {
        const float v = uacc[i4 >> 3];
        ob4[COND * 8 + i4] = make_float4(v, v, v, v);
    }
}

extern "C" void kernel_launch(void* const* d_in, const int* in_sizes, int n_in,
                              void* d_out, int out_size, void* d_ws, size_t ws_size,
                              hipStream_t stream) {
    const int*   tp        = (const int*)  d_in[0];
    const int*   loc       = (const int*)  d_in[1];
    const float* emb       = (const float*)d_in[2];
    const int*   st        = (const int*)  d_in[3];
    const float* loc_emb   = (const float*)d_in[4];
    const float* noise     = (const float*)d_in[5];
    const int*   tstep     = (const int*)  d_in[6];
    const float* w1        = (const float*)d_in[7];
    const float* w2        = (const float*)d_in[8];
    const float* b2        = (const float*)d_in[9];
    const float* wc        = (const float*)d_in[10];
    const float* alpha_hat = (const float*)d_in[11];
    float* out = (float*)d_out;

    unsigned short* w2b    = (unsigned short*)d_ws;                 // 51,200 B
    unsigned short* te_tab = (unsigned short*)((char*)d_ws + 51200); // 12,544 B

    prep<<<38, 256, 0, stream>>>(w2, w2b, te_tab);
    const int nb = in_sizes[0];   // 2048
    fused_cond<<<nb, 512, 0, stream>>>(tp, loc, emb, st, loc_emb, noise,
                                       tstep, w1, w2b, te_tab, b2, wc, alpha_hat, out);
}

// Round 4
// 92.139 us; speedup vs baseline: 7.0494x; 1.6659x over previous
//
#include <hip/hip_runtime.h>
#include <hip/hip_bf16.h>

#define LSEQ   200
#define LPAD   208
#define EMB    32
#define TDIM   128
#define COND   160
#define ROWS   321
#define MASK_T 48
#define LL_LDB 80      // LL row stride bytes (64B data + 16B pad -> 2-way banks, free)

typedef __attribute__((ext_vector_type(8))) short  short8;
typedef __attribute__((ext_vector_type(4))) float  f32x4;

__device__ __forceinline__ float bf2f(unsigned short u) {
    union { unsigned int i; float f; } v; v.i = ((unsigned int)u) << 16; return v.f;
}
__device__ __forceinline__ unsigned int f2bf(float f) {
    union { float f; unsigned int i; } v; v.f = f;
    unsigned int x = v.i;
    return ((x + 0x7fffu + ((x >> 16) & 1u)) >> 16);   // RNE, low 16
}
__device__ __forceinline__ unsigned int pack2(float lo, float hi) {
    return f2bf(lo) | (f2bf(hi) << 16);
}
__device__ __forceinline__ short8 pack8(float4 a, float4 b) {
    union { short8 s; unsigned int u[4]; } r;
    r.u[0] = pack2(a.x, a.y); r.u[1] = pack2(a.z, a.w);
    r.u[2] = pack2(b.x, b.y); r.u[3] = pack2(b.z, b.w);
    return r.s;
}

// ---- prep: per t in [0,49): te_tab row (bf16) + T1 = te@w1[:,32:]^T (fp32)
//      + T2 = te@w2[:,32:]^T (bf16); rows t==48 zeroed in T1/T2 (mask semantics).
__global__ void prep(const float* __restrict__ w1, const float* __restrict__ w2,
                     unsigned short* __restrict__ te_tab, float* __restrict__ T1,
                     unsigned short* __restrict__ T2g) {
    __shared__ float te128[TDIM];
    const int t   = blockIdx.x;        // 0..48
    const int tid = threadIdx.x;       // 256
    if (tid < 64) {
        const float dv = __expf(-0.14391156f * (float)tid);   // 10000^(-tid/64)
        const float a  = (float)t * dv;
        const float s  = __sinf(a), c = __cosf(a);
        te128[2 * tid] = s; te128[2 * tid + 1] = c;
        ((unsigned int*)te_tab)[t * 64 + tid] = pack2(s, c);
    }
    __syncthreads();
    if (tid < COND) {
        float s1 = 0.0f, s2 = 0.0f;
        const float* w1r = w1 + tid * COND + EMB;
        const float* w2r = w2 + tid * COND + EMB;
        #pragma unroll 8
        for (int j = 0; j < TDIM; ++j) {
            s1 = fmaf(te128[j], w1r[j], s1);
            s2 = fmaf(te128[j], w2r[j], s2);
        }
        if (t == MASK_T) { s1 = 0.0f; s2 = 0.0f; }
        T1[t * COND + tid]  = s1;
        T2g[t * COND + tid] = (unsigned short)f2bf(s2);
    }
}

__global__ __launch_bounds__(256, 6)
void fused_cond(const int*   __restrict__ tp,
                const int*   __restrict__ loc,
                const float* __restrict__ emb,
                const int*   __restrict__ st,        // [B][L][2]
                const float* __restrict__ loc_emb,   // [V][32] fp32
                const float* __restrict__ noise,
                const int*   __restrict__ tstep,
                const float* __restrict__ w1,        // [160][160] fp32 (cols 0..31 used)
                const float* __restrict__ w2,        // [160][160] fp32 (cols 0..31 used)
                const unsigned short* __restrict__ te_tab, // [49][128] bf16
                const float* __restrict__ T1,        // [49][160] fp32
                const unsigned short* __restrict__ T2g,    // [49][160] bf16
                const float* __restrict__ b2,
                const float* __restrict__ wc,
                const float* __restrict__ alpha_hat,
                float* __restrict__ out)             // [B][321][32]
{
    __shared__ __attribute__((aligned(16))) unsigned char LL[LPAD * LL_LDB]; // 16,640 B
    __shared__ float score[LPAD];
    __shared__ float side[COND];
    __shared__ float m1s[COND];
    __shared__ float wcs[COND];
    __shared__ float uacc[COND];          // [uemb_loc(32) | uemb_te(128)]
    __shared__ float mloc[EMB];
    __shared__ float sb[49];
    __shared__ unsigned int cnt[49];
    __shared__ unsigned short ttr[LPAD];

    const int b   = blockIdx.x;
    const int tid = threadIdx.x;
    float* outb = out + (size_t)b * (ROWS * EMB);

    // ---- P0: init accumulators + side + noisy row ----
    for (int i = tid; i < 49; i += 256) { cnt[i] = 0u; sb[i] = 0.0f; }
    if (tid < LPAD) score[tid] = 0.0f;
    if (tid < COND) wcs[tid] = wc[tid];
    if (tid < EMB)  mloc[tid] = 0.0f;
    if (tid < EMB)  uacc[tid] = 0.0f;     // only loc cols are atomic targets
    if (tid < TDIM) {
        side[tid] = bf2f(te_tab[tp[b] * TDIM + tid]);
    } else if (tid < COND) {
        side[tid] = loc_emb[(size_t)(loc[b] - 1) * EMB + (tid - TDIM)];
    } else if (tid < COND + EMB) {
        const int   e = tid - COND;
        const float a = alpha_hat[tstep[b]];
        outb[320 * EMB + e] = sqrtf(a) * emb[b * EMB + e]
                            + sqrtf(1.0f - a) * noise[b * EMB + e];
    }
    __syncthreads();

    // ---- P1: tt/cnt histogram + LL staging (loc rows, bf16) ----
    if (tid < LPAD) {
        unsigned short t16 = 0;
        if (tid < LSEQ) {
            const int2 sv = ((const int2*)st)[b * LSEQ + tid];
            t16 = (unsigned short)sv.y;
            if (sv.y != MASK_T) atomicAdd(&cnt[sv.y], 1u);
        }
        ttr[tid] = t16;
    }
    for (int ci = tid; ci < LPAD * 4; ci += 256) {       // 16B chunks
        const int l = ci >> 2, q = ci & 3;
        uint4 val = make_uint4(0, 0, 0, 0);
        if (l < LSEQ) {
            const int s = ((const int2*)st)[b * LSEQ + l].x;
            const float4* lr = (const float4*)(loc_emb + (size_t)(s - 1) * EMB + q * 8);
            const float4 v0 = lr[0], v1 = lr[1];
            val = make_uint4(pack2(v0.x, v0.y), pack2(v0.z, v0.w),
                             pack2(v1.x, v1.y), pack2(v1.z, v1.w));
        }
        *(uint4*)(LL + l * LL_LDB + q * 16) = val;
    }
    __syncthreads();

    // ---- P2: mean_loc partial column sums ----
    {
        const int c = tid & 31, g = tid >> 5;            // 8 row-groups x 32 cols
        const unsigned char* p = LL + g * 25 * LL_LDB + 2 * c;
        float s = 0.0f;
        #pragma unroll 5
        for (int l = 0; l < 25; ++l)
            s += bf2f(*(const unsigned short*)(p + l * LL_LDB));
        atomicAdd(&mloc[c], s);
    }
    __syncthreads();

    // ---- P3: m1 = b2 + mean_loc@w1[:, :32]^T + cnt@T1/200 ----
    if (tid < COND) {
        float m = b2[tid];
        const float4* w1r = (const float4*)(w1 + tid * COND);
        #pragma unroll
        for (int j4 = 0; j4 < 8; ++j4) {
            const float4 wv4 = w1r[j4];
            m = fmaf(mloc[j4 * 4 + 0] * 0.005f, wv4.x, m);
            m = fmaf(mloc[j4 * 4 + 1] * 0.005f, wv4.y, m);
            m = fmaf(mloc[j4 * 4 + 2] * 0.005f, wv4.z, m);
            m = fmaf(mloc[j4 * 4 + 3] * 0.005f, wv4.w, m);
        }
        float mt = 0.0f;
        for (int t = 0; t < 49; ++t)
            mt = fmaf((float)cnt[t], T1[t * COND + tid], mt);
        m1s[tid] = m + mt * 0.005f;
    }
    __syncthreads();

    // ---- P4: MFMA (K=32) logits_loc + T2 gather + sigmoid + wc-dot -> score ----
    const int wv = tid >> 6, lane = tid & 63, lc = lane & 15, lg = lane >> 4;
    const int nn = (wv < 2) ? 3 : 2;                     // tiles {wv, wv+4, wv+8?}
    short8 bf0, bf1, bf2v = short8{0,0,0,0,0,0,0,0};
    float m10, m11, m12 = 0.0f, wc0, wc1, wc2 = 0.0f;
    {
        const float4* r0 = (const float4*)(w2 + (wv * 16 + lc) * COND + lg * 8);
        bf0 = pack8(r0[0], r0[1]);
        const float4* r1 = (const float4*)(w2 + ((wv + 4) * 16 + lc) * COND + lg * 8);
        bf1 = pack8(r1[0], r1[1]);
        m10 = m1s[wv * 16 + lc];       wc0 = wcs[wv * 16 + lc];
        m11 = m1s[(wv + 4) * 16 + lc]; wc1 = wcs[(wv + 4) * 16 + lc];
        if (nn == 3) {
            const float4* r2 = (const float4*)(w2 + ((wv + 8) * 16 + lc) * COND + lg * 8);
            bf2v = pack8(r2[0], r2[1]);
            m12 = m1s[(wv + 8) * 16 + lc]; wc2 = wcs[(wv + 8) * 16 + lc];
        }
    }

    for (int m = 0; m < 13; ++m) {
        const short8 av = *(const short8*)(LL + (m * 16 + lc) * LL_LDB + lg * 16);
        f32x4 a0 = {0,0,0,0}, a1 = {0,0,0,0}, a2 = {0,0,0,0};
        a0 = __builtin_amdgcn_mfma_f32_16x16x32_bf16(av, bf0, a0, 0, 0, 0);
        a1 = __builtin_amdgcn_mfma_f32_16x16x32_bf16(av, bf1, a1, 0, 0, 0);
        if (nn == 3)
            a2 = __builtin_amdgcn_mfma_f32_16x16x32_bf16(av, bf2v, a2, 0, 0, 0);

        f32x4 sc;
        #pragma unroll
        for (int r = 0; r < 4; ++r) {
            const int row = m * 16 + lg * 4 + r;         // D: col=lc, row as computed
            const unsigned short* t2r = T2g + (int)ttr[row] * COND;
            float s = wc0 / (1.0f + __expf(-(a0[r] + m10 + bf2f(t2r[wv * 16 + lc]))));
            s      += wc1 / (1.0f + __expf(-(a1[r] + m11 + bf2f(t2r[(wv + 4) * 16 + lc]))));
            if (nn == 3)
                s  += wc2 / (1.0f + __expf(-(a2[r] + m12 + bf2f(t2r[(wv + 8) * 16 + lc]))));
            sc[r] = s;
        }
        #pragma unroll
        for (int sh = 1; sh < 16; sh <<= 1) {
            sc[0] += __shfl_xor(sc[0], sh);
            sc[1] += __shfl_xor(sc[1], sh);
            sc[2] += __shfl_xor(sc[2], sh);
            sc[3] += __shfl_xor(sc[3], sh);
        }
        if (lc == 0) {
            #pragma unroll
            for (int r = 0; r < 4; ++r) {
                const int row = m * 16 + lg * 4 + r;
                if (row < LSEQ) atomicAdd(&score[row], sc[r]);
            }
        }
    }
    __syncthreads();

    // ---- P5: score histogram (sb) + uemb_loc column sums ----
    if (tid < LSEQ) {
        const int tt = ttr[tid];
        if (tt != MASK_T) atomicAdd(&sb[tt], score[tid]);
    }
    {
        const int c = tid & 31, g = tid >> 5;
        const unsigned char* p = LL + g * 25 * LL_LDB + 2 * c;
        const float* sr = score + g * 25;
        float s = 0.0f;
        #pragma unroll 5
        for (int l = 0; l < 25; ++l)
            s = fmaf(sr[l], bf2f(*(const unsigned short*)(p + l * LL_LDB)), s);
        atomicAdd(&uacc[c], s);
    }
    __syncthreads();

    // ---- P5b: uemb_te[j] = sum_t sb[t]*te_tab[t][j]  (sb[48]==0) ----
    if (tid < TDIM) {
        float s = 0.0f;
        for (int t = 0; t < 49; ++t)
            s = fmaf(sb[t], bf2f(te_tab[t * TDIM + tid]), s);
        uacc[EMB + tid] = s;
    }
    __syncthreads();

    // ---- P6: broadcast writes: ST_info rows 0..159, user_info rows 160..319 ----
    float4* ob4 = (float4*)outb;
    #pragma unroll
    for (int t = 0; t < 5; ++t) {
        const int i4 = tid + t * 256;
        const float v = side[i4 >> 3];
        ob4[i4] = make_float4(v, v, v, v);
    }
    #pragma unroll
    for (int t = 0; t < 5; ++t) {
        const int i4 = tid + t * 256;
        const float v = uacc[i4 >> 3];
        ob4[COND * 8 + i4] = make_float4(v, v, v, v);
    }
}

extern "C" void kernel_launch(void* const* d_in, const int* in_sizes, int n_in,
                              void* d_out, int out_size, void* d_ws, size_t ws_size,
                              hipStream_t stream) {
    const int*   tp        = (const int*)  d_in[0];
    const int*   loc       = (const int*)  d_in[1];
    const float* emb       = (const float*)d_in[2];
    const int*   st        = (const int*)  d_in[3];
    const float* loc_emb   = (const float*)d_in[4];
    const float* noise     = (const float*)d_in[5];
    const int*   tstep     = (const int*)  d_in[6];
    const float* w1        = (const float*)d_in[7];
    const float* w2        = (const float*)d_in[8];
    const float* b2        = (const float*)d_in[9];
    const float* wc        = (const float*)d_in[10];
    const float* alpha_hat = (const float*)d_in[11];
    float* out = (float*)d_out;

    float*          T1     = (float*)d_ws;                               // 31,360 B
    unsigned short* te_tab = (unsigned short*)((char*)d_ws + 31360);     // 12,544 B
    unsigned short* T2g    = (unsigned short*)((char*)d_ws + 43904);     // 15,680 B

    prep<<<49, 256, 0, stream>>>(w1, w2, te_tab, T1, T2g);
    const int nb = in_sizes[0];   // 2048
    fused_cond<<<nb, 256, 0, stream>>>(tp, loc, emb, st, loc_emb, noise, tstep,
                                       w1, w2, te_tab, T1, T2g, b2, wc, alpha_hat, out);
}